// Round 5
// baseline (480.010 us; speedup 1.0000x reference)
//
#include <hip/hip_runtime.h>

#define Bb 256
#define Tt 512
#define Kk 128
#define LN2F 0.69314718055994531f
#define SC9 0.001953125f   /* 2^-9 fixed per-step renorm (exact) */

typedef _Float16 half4_t __attribute__((ext_vector_type(4)));
typedef _Float16 half2_t __attribute__((ext_vector_type(2)));
typedef float    floatx4 __attribute__((ext_vector_type(4)));

// cvt_pkrtz returns __fp16x2; bit-cast to our half2_t (_Float16x2)
__device__ __forceinline__ half2_t pkrtz(float a, float b) {
    return __builtin_bit_cast(half2_t, __builtin_amdgcn_cvt_pkrtz(a, b));
}

// ---------------- pass 1: gold-path score (1 block / batch) ---------------
__global__ __launch_bounds__(256) void score_kernel(const float* __restrict__ lg,
                                                    const int* __restrict__ labels,
                                                    const int* __restrict__ seq_lens,
                                                    const float* __restrict__ trans,
                                                    float* __restrict__ out) {
    __shared__ float red[4];
    const int b = blockIdx.x, tid = threadIdx.x, lane = tid & 63, wave = tid >> 6;
    const int* lab = labels + b * Tt;
    const float* L = lg + (size_t)b * Tt * Kk;
    const int Lb = seq_lens[b];
    float s = 0.f;
    #pragma unroll
    for (int tt = 0; tt < Tt; tt += 256) {
        int t = tt + tid;
        if (t < Lb) {
            int cur = lab[t];
            s += L[(size_t)t * Kk + cur];
            if (t >= 1) s += trans[lab[t - 1] * Kk + cur];
        }
    }
    #pragma unroll
    for (int o = 32; o > 0; o >>= 1) s += __shfl_down(s, o, 64);
    if (lane == 0) red[wave] = s;
    __syncthreads();
    if (tid == 0) atomicAdd(out, -(red[0] + red[1] + red[2] + red[3]));
}

// ---------------- pass 2: forward recursion, 1 wave = 16 batches ----------
// State S[k][b] (128x16, linear, power-of-2 renorm) in B-frag registers;
// E^T = exp(trans)^T constant in A-frag registers.
// v_mfma_f32_16x16x16f16: D slot (q,r)->m=4q+r == B slot (q,j)->k=4q+j, and
// n-map == c for both => D chains directly into next step's B (HW-verified R4,
// absmax 0). Fixed 2^-9/step scaling; exact per-column exponent correction
// every 8 steps (growth ~2^8.6 +- 0.3, CLT-concentrated).
__global__ __launch_bounds__(64, 1) void crf_fwd(const float* __restrict__ lg,
                                                 const float* __restrict__ trans,
                                                 const int* __restrict__ seq_lens,
                                                 float* __restrict__ out) {
    const int lane = threadIdx.x;
    const int q = lane >> 4, c = lane & 15;
    const int b0 = blockIdx.x * 16;
    const int Lc = seq_lens[b0 + c];          // per-column seq len
    int Lmax = Lc;
    Lmax = max(Lmax, __shfl_xor(Lmax, 1, 64));
    Lmax = max(Lmax, __shfl_xor(Lmax, 2, 64));
    Lmax = max(Lmax, __shfl_xor(Lmax, 4, 64));
    Lmax = max(Lmax, __shfl_xor(Lmax, 8, 64));

    // E fragments: A slot (q,c,reg j) = E^T[m=16mt+c][k=16kc+4q+j]
    half4_t E[8][8];
    #pragma unroll
    for (int mt = 0; mt < 8; ++mt)
        #pragma unroll
        for (int kc = 0; kc < 8; ++kc) {
            half4_t e;
            #pragma unroll
            for (int j = 0; j < 4; ++j)
                e[j] = (_Float16)__expf(trans[(16 * kc + 4 * q + j) * Kk + 16 * mt + c]);
            E[mt][kc] = e;
        }

    const float* Gb = lg + (size_t)(b0 + c) * Tt * Kk;
    auto loadfrag = [&](int tt, int mt) -> float4 {
        return *(const float4*)(Gb + (size_t)tt * Kk + 16 * mt + 4 * q);
    };

    half4_t S[8];
    int Csum = 0;

    auto freeze = [&](int T) {
        if (__any(T == Lc - 1)) {
            float cs = 0.f;
            #pragma unroll
            for (int mt = 0; mt < 8; ++mt)
                cs += (float)S[mt][0] + (float)S[mt][1] +
                      (float)S[mt][2] + (float)S[mt][3];
            cs += __shfl_xor(cs, 16, 64);
            cs += __shfl_xor(cs, 32, 64);
            if (T == Lc - 1 && q == 0)
                atomicAdd(out, __logf(cs) + (float)Csum * LN2F);
        }
    };

    // ---- t = 0: S = exp(logits[:,0,:]) ----
    #pragma unroll
    for (int mt = 0; mt < 8; ++mt) {
        float4 v = loadfrag(0, mt);
        half2_t lo = pkrtz(__expf(v.x), __expf(v.y));
        half2_t hi = pkrtz(__expf(v.z), __expf(v.w));
        S[mt] = (half4_t){lo[0], lo[1], hi[0], hi[1]};
    }
    freeze(0);

    float4 bufA[8], bufB[8];
    #pragma unroll
    for (int mt = 0; mt < 8; ++mt) bufA[mt] = loadfrag(1, mt);
    #pragma unroll
    for (int mt = 0; mt < 8; ++mt) bufB[mt] = loadfrag(2 < Tt - 1 ? 2 : Tt - 1, mt);

    auto step = [&](int T, float4 (&buf)[8], int TN) {
        floatx4 D[8];
        #pragma unroll
        for (int mt = 0; mt < 8; ++mt) D[mt] = (floatx4){0.f, 0.f, 0.f, 0.f};
        #pragma unroll
        for (int kc = 0; kc < 8; ++kc)
            #pragma unroll
            for (int mt = 0; mt < 8; ++mt)
                D[mt] = __builtin_amdgcn_mfma_f32_16x16x16f16(E[mt][kc], S[kc], D[mt], 0, 0, 0);
        const int tclamp = TN > Tt - 1 ? Tt - 1 : TN;
        #pragma unroll
        for (int mt = 0; mt < 8; ++mt) {
            half2_t pl = pkrtz(__expf(buf[mt].x), __expf(buf[mt].y));
            half2_t ph = pkrtz(__expf(buf[mt].z), __expf(buf[mt].w));
            half2_t lo = pkrtz(D[mt][0] * SC9, D[mt][1] * SC9);
            half2_t hi = pkrtz(D[mt][2] * SC9, D[mt][3] * SC9);
            lo *= pl;                          // v_pk_mul_f16
            hi *= ph;
            S[mt] = (half4_t){lo[0], lo[1], hi[0], hi[1]};
            buf[mt] = loadfrag(tclamp, mt);    // prefetch t+2 (after consume)
        }
        Csum += 9;
        freeze(T);
        if ((T & 7) == 7) {                    // exact per-column correction
            float mx = 0.f;
            #pragma unroll
            for (int mt = 0; mt < 8; ++mt)
                mx = fmaxf(mx, fmaxf(fmaxf((float)S[mt][0], (float)S[mt][1]),
                                     fmaxf((float)S[mt][2], (float)S[mt][3])));
            mx = fmaxf(mx, __shfl_xor(mx, 16, 64));
            mx = fmaxf(mx, __shfl_xor(mx, 32, 64));
            int e = ((__builtin_bit_cast(int, mx) >> 23) & 0xff) - 127;
            e = e < -14 ? -14 : (e > 14 ? 14 : e);
            const _Float16 sf = (_Float16)__builtin_bit_cast(float, (127 - e) << 23);
            const half4_t sv = (half4_t){sf, sf, sf, sf};
            #pragma unroll
            for (int mt = 0; mt < 8; ++mt) S[mt] *= sv;   // exact pow2 in f16
            Csum += e;
        }
    };

    int t = 1;
    for (; t + 1 < Lmax; t += 2) {
        step(t, bufA, t + 2);
        step(t + 1, bufB, t + 3);
    }
    if (t < Lmax) step(t, bufA, t + 2);
}

extern "C" void kernel_launch(void* const* d_in, const int* in_sizes, int n_in,
                              void* d_out, int out_size, void* d_ws, size_t ws_size,
                              hipStream_t stream) {
    const float* logits   = (const float*)d_in[0];
    const int*   labels   = (const int*)d_in[1];
    const int*   seq_lens = (const int*)d_in[2];
    const float* trans    = (const float*)d_in[3];
    float* out = (float*)d_out;

    hipMemsetAsync(out, 0, sizeof(float), stream);
    score_kernel<<<dim3(Bb), dim3(256), 0, stream>>>(logits, labels, seq_lens, trans, out);
    crf_fwd<<<dim3(Bb / 16), dim3(64), 0, stream>>>(logits, trans, seq_lens, out);
}